// Round 1
// baseline (2267.412 us; speedup 1.0000x reference)
//
#include <hip/hip_runtime.h>
#include <math.h>

#define HWc 16384
#define Wd 128
#define Hd 128

// ---------------------------------------------------------------------------
// Generic 3x3 conv (cin -> 64) + BN + ReLU. Optional per-pixel input multiplier
// (samul) fused at staging (used for att = attpre * sa in the final conv).
// Block: 256 threads = 16x16 output pixels; each thread accumulates 64 oc.
// ---------------------------------------------------------------------------
__global__ __launch_bounds__(256) void conv3x3_bn_kernel(
    const float* __restrict__ in, const float* __restrict__ wgt,
    const float* __restrict__ bng, const float* __restrict__ bnb,
    const float* __restrict__ bnm, const float* __restrict__ bnv,
    const float* __restrict__ samul, float* __restrict__ out, int cin)
{
    __shared__ float tile[18*18];
    __shared__ float wl[576];
    __shared__ float sc[64], sh[64];
    __shared__ float satile[18*18];
    int tid = threadIdx.x;
    int tileid = blockIdx.x; int b = blockIdx.y;
    int th = tileid >> 3, tw = tileid & 7;
    int h0 = th*16 - 1, w0 = tw*16 - 1;
    if (tid < 64) {
        float inv = rsqrtf(bnv[tid] + 1e-5f);
        float s = bng[tid]*inv;
        sc[tid] = s;
        sh[tid] = bnb[tid] - bnm[tid]*s;
    }
    if (samul) {
        const float* sp = samul + (size_t)b*HWc;
        for (int i = tid; i < 324; i += 256) {
            int y = i/18, x = i%18;
            int hh = h0+y, ww = w0+x;
            satile[i] = (hh>=0 && hh<Hd && ww>=0 && ww<Wd) ? sp[hh*Wd+ww] : 0.f;
        }
    }
    float acc[64];
    #pragma unroll
    for (int i=0;i<64;i++) acc[i]=0.f;
    int py = tid>>4, px = tid&15;
    for (int ci=0; ci<cin; ci++){
        __syncthreads();
        const float* inp = in + ((size_t)b*cin + ci)*HWc;
        for (int i = tid; i < 324; i += 256) {
            int y=i/18, x=i%18; int hh=h0+y, ww=w0+x;
            float v = (hh>=0&&hh<Hd&&ww>=0&&ww<Wd) ? inp[hh*Wd+ww] : 0.f;
            if (samul) v *= satile[i];
            tile[i]=v;
        }
        for (int i = tid; i < 576; i += 256) {
            int oc = i/9, t = i - oc*9;
            wl[i] = wgt[((size_t)oc*cin + ci)*9 + t];
        }
        __syncthreads();
        float v[9];
        #pragma unroll
        for (int dy=0;dy<3;dy++)
            #pragma unroll
            for (int dx=0;dx<3;dx++)
                v[dy*3+dx] = tile[(py+dy)*18 + px+dx];
        #pragma unroll
        for (int oc=0;oc<64;oc++){
            float a = acc[oc];
            #pragma unroll
            for (int t=0;t<9;t++) a = fmaf(wl[oc*9+t], v[t], a);
            acc[oc]=a;
        }
    }
    int hh = h0+1+py, ww = w0+1+px;
    size_t base = (size_t)b*64*HWc + hh*Wd + ww;
    #pragma unroll
    for (int oc=0;oc<64;oc++){
        float y = fmaf(acc[oc], sc[oc], sh[oc]);
        out[base + (size_t)oc*HWc] = fmaxf(y, 0.f);
    }
}

// ---------------------------------------------------------------------------
// Combine conv: out = conv3x3(cat([fusion1, edge*(x1+1)], ch), combine_w) + b.
// Channels 64..127 (edgeterm) are computed on the fly during LDS staging:
// edgeterm[c] = (conv3x3(E, edge_w[c]) + edge_b[c]) * (x1[c]+1).
// ---------------------------------------------------------------------------
__global__ __launch_bounds__(256) void combine_kernel(
    const float* __restrict__ fusion1, const float* __restrict__ Ein,
    const float* __restrict__ x1,
    const float* __restrict__ edge_w, const float* __restrict__ edge_b,
    const float* __restrict__ cw, const float* __restrict__ cb,
    float* __restrict__ out)
{
    __shared__ float tile[18*18];
    __shared__ float e20[20*20];
    __shared__ float wl[576];
    int tid = threadIdx.x;
    int tileid = blockIdx.x; int b = blockIdx.y;
    int th = tileid >> 3, tw = tileid & 7;
    int h0 = th*16 - 1, w0 = tw*16 - 1;
    {
        const float* ep = Ein + (size_t)b*HWc;
        for (int i=tid;i<400;i+=256){
            int y=i/20, x=i%20; int hh=h0-1+y, ww=w0-1+x;
            e20[i] = (hh>=0&&hh<Hd&&ww>=0&&ww<Wd) ? ep[hh*Wd+ww] : 0.f;
        }
    }
    float acc[64];
    #pragma unroll
    for (int i=0;i<64;i++) acc[i]=0.f;
    int py = tid>>4, px = tid&15;
    for (int ci=0; ci<128; ci++){
        __syncthreads();
        if (ci < 64) {
            const float* inp = fusion1 + ((size_t)b*64 + ci)*HWc;
            for (int i=tid;i<324;i+=256){
                int y=i/18,x=i%18; int hh=h0+y, ww=w0+x;
                tile[i] = (hh>=0&&hh<Hd&&ww>=0&&ww<Wd)? inp[hh*Wd+ww] : 0.f;
            }
        } else {
            int c = ci - 64;
            const float* xp = x1 + ((size_t)b*64 + c)*HWc;
            float ewv[9];
            #pragma unroll
            for (int t=0;t<9;t++) ewv[t] = edge_w[c*9+t];
            float eb = edge_b[c];
            for (int i=tid;i<324;i+=256){
                int y=i/18,x=i%18; int hh=h0+y, ww=w0+x;
                float val = 0.f;
                if (hh>=0&&hh<Hd&&ww>=0&&ww<Wd){
                    float ec = eb;
                    #pragma unroll
                    for (int t=0;t<9;t++){
                        int dy=t/3, dx=t%3;
                        ec = fmaf(ewv[t], e20[(y+dy)*20 + x+dx], ec);
                    }
                    val = ec * (xp[hh*Wd+ww] + 1.0f);
                }
                tile[i]=val;
            }
        }
        for (int i=tid;i<576;i+=256){
            int oc=i/9, t=i-oc*9;
            wl[i] = cw[((size_t)oc*128 + ci)*9 + t];
        }
        __syncthreads();
        float v[9];
        #pragma unroll
        for (int dy=0;dy<3;dy++)
            #pragma unroll
            for (int dx=0;dx<3;dx++)
                v[dy*3+dx] = tile[(py+dy)*18 + px+dx];
        #pragma unroll
        for (int oc=0;oc<64;oc++){
            float a = acc[oc];
            #pragma unroll
            for (int t=0;t<9;t++) a = fmaf(wl[oc*9+t], v[t], a);
            acc[oc]=a;
        }
    }
    int hh=h0+1+py, ww=w0+1+px;
    size_t base=(size_t)b*64*HWc + hh*Wd+ww;
    #pragma unroll
    for (int oc=0;oc<64;oc++)
        out[base + (size_t)oc*HWc] = acc[oc] + cb[oc];
}

// ---------------------------------------------------------------------------
// z maps: z_t = sum_c down2_w[c,t]*x1[c]  (and z1 for down1). 9 taps each.
// These let us compute conv(upsample(x1), down2_w) without materializing X:
// conv and channel-contraction commute with the (per-channel, linear) upsample.
// ---------------------------------------------------------------------------
__global__ __launch_bounds__(256) void zmaps_kernel(const float* __restrict__ x1,
    const float* __restrict__ w2, const float* __restrict__ w1,
    float* __restrict__ z, float* __restrict__ z1)
{
    int idx = blockIdx.x*256 + threadIdx.x;
    int b = idx >> 14; int p = idx & 16383;
    const float* xp = x1 + (size_t)b*64*HWc + p;
    float a2[9], a1[9];
    #pragma unroll
    for (int t=0;t<9;t++){ a2[t]=0.f; a1[t]=0.f; }
    for (int c=0;c<64;c++){
        float v = xp[(size_t)c*HWc];
        #pragma unroll
        for (int t=0;t<9;t++){
            a2[t] = fmaf(w2[c*9+t], v, a2[t]);
            a1[t] = fmaf(w1[c*9+t], v, a1[t]);
        }
    }
    #pragma unroll
    for (int t=0;t<9;t++){
        z [((size_t)b*9+t)*HWc + p] = a2[t];
        z1[((size_t)b*9+t)*HWc + p] = a1[t];
    }
}

__global__ __launch_bounds__(256) void xin_kernel(const float* __restrict__ z1,
    const float* __restrict__ b1p, float* __restrict__ xin)
{
    int idx = blockIdx.x*256+threadIdx.x;
    int b=idx>>14; int p=idx&16383;
    int i=p>>7, j=p&127;
    float acc = b1p[0];
    #pragma unroll
    for (int t=0;t<9;t++){
        int ii=i+t/3-1, jj=j+t%3-1;
        if (ii>=0&&ii<Hd&&jj>=0&&jj<Wd)
            acc += z1[((size_t)b*9+t)*HWc + ii*Wd+jj];
    }
    xin[idx]=acc;
}

// ---------------------------------------------------------------------------
// X_in(i,j) = down2_b + sum_t bilin(z_t)(i+dy, j+dx) on the 256x256 domain
// (zero pad), then Haar DWT -> cA and E=|LH|+|HL|+|HH| at 128x128.
// ---------------------------------------------------------------------------
__global__ __launch_bounds__(256) void dwt_kernel(const float* __restrict__ z,
    const float* __restrict__ b2p, float* __restrict__ cA, float* __restrict__ Eo)
{
    int idx = blockIdx.x*256 + threadIdx.x;
    int b = idx >> 14; int p = idx & 16383;
    int u = p >> 7, v = p & 127;
    float b2 = b2p[0];
    int rlo[4], rhi[4]; float rf[4]; bool rv[4];
    int clo[4], chi[4]; float cf[4]; bool cvv[4];
    #pragma unroll
    for (int k=0;k<4;k++){
        int r = 2*u - 1 + k;
        rv[k] = (r>=0 && r<256);
        int rr = rv[k] ? r : 0;
        float cc = ((float)rr * 127.0f) / 255.0f;
        int lo = (int)cc;
        rlo[k]=lo; rhi[k]=min(lo+1,127); rf[k]=cc-(float)lo;
        int s = 2*v - 1 + k;
        cvv[k] = (s>=0 && s<256);
        int ss = cvv[k] ? s : 0;
        float c2 = ((float)ss * 127.0f) / 255.0f;
        int lo2=(int)c2;
        clo[k]=lo2; chi[k]=min(lo2+1,127); cf[k]=c2-(float)lo2;
    }
    float Xin[4] = {b2,b2,b2,b2};
    #pragma unroll
    for (int t=0;t<9;t++){
        int dy=t/3, dx=t%3;
        const float* zp = z + ((size_t)b*9 + t)*HWc;
        #pragma unroll
        for (int e=0;e<4;e++){
            int ey=e>>1, ex=e&1;
            int k=ey+dy, l=ex+dx;
            if (rv[k] && cvv[l]){
                const float* row0 = zp + rlo[k]*Wd;
                const float* row1 = zp + rhi[k]*Wd;
                float v00=row0[clo[l]], v01=row0[chi[l]];
                float v10=row1[clo[l]], v11=row1[chi[l]];
                float fc_=cf[l], fr_=rf[k];
                float top = v00*(1.0f-fc_) + v01*fc_;
                float bot = v10*(1.0f-fc_) + v11*fc_;
                Xin[e] += top*(1.0f-fr_) + bot*fr_;
            }
        }
    }
    float a=Xin[0], bb=Xin[1], c_=Xin[2], d_=Xin[3];
    float LL=0.5f*( a+bb+c_+d_);
    float LH=0.5f*(-a-bb+c_+d_);
    float HL=0.5f*(-a+bb-c_+d_);
    float HH=0.5f*( a-bb-c_+d_);
    cA[(size_t)b*HWc + p] = LL;
    Eo[(size_t)b*HWc + p] = fabsf(LH)+fabsf(HL)+fabsf(HH);
}

// ---------------------------------------------------------------------------
// wt = conv3x3(cA, wt_w)+wt_b ; gab = sigmoid(conv7x7(x_in, mean-gabor)).
// Mean over the 4 gabor output channels == conv with the channel-mean kernel.
// ---------------------------------------------------------------------------
__global__ __launch_bounds__(256) void wtgab_kernel(const float* __restrict__ cA,
    const float* __restrict__ xin, const float* __restrict__ wtw, const float* __restrict__ wtb,
    float* __restrict__ wtgab)
{
    __shared__ float gm[49];
    int tid=threadIdx.x;
    if (tid<49){
        int ky=tid/7, kx=tid%7;
        float yy=(float)(ky-3), xx=(float)(kx-3);
        float s=0.f;
        for (int t=0;t<4;t++){
            float theta = (float)t * 0.7853981633974483f;
            float ct=cosf(theta), st=sinf(theta);
            float xt = xx*ct + yy*st;
            float yt = -xx*st + yy*ct;
            s += expf(-0.5f*(xt*xt*(1.0f/16.0f) + yt*yt*(1.0f/64.0f))) * cosf(0.6283185307179586f*xt);
        }
        gm[tid]=0.25f*s;
    }
    __syncthreads();
    int idx = blockIdx.x*256+tid;
    int b=idx>>14; int p=idx&16383;
    int i=p>>7, j=p&127;
    float wacc = wtb[0];
    #pragma unroll
    for (int t=0;t<9;t++){
        int ii=i+t/3-1, jj=j+t%3-1;
        if (ii>=0&&ii<Hd&&jj>=0&&jj<Wd)
            wacc = fmaf(wtw[t], cA[b*HWc + ii*Wd+jj], wacc);
    }
    float g=0.f;
    for (int k=0;k<49;k++){
        int ii=i+k/7-3, jj=j+k%7-3;
        if (ii>=0&&ii<Hd&&jj>=0&&jj<Wd)
            g = fmaf(gm[k], xin[b*HWc + ii*Wd+jj], g);
    }
    wtgab[((size_t)b*2)*HWc + p] = wacc;
    wtgab[((size_t)b*2+1)*HWc + p] = 1.0f/(1.0f+expf(-g));
}

// ---------------------------------------------------------------------------
// CBAM pieces
// ---------------------------------------------------------------------------
__global__ __launch_bounds__(256) void pool_kernel(const float* __restrict__ fusion,
    float* __restrict__ pavg, float* __restrict__ pmax)
{
    int bc = blockIdx.x; int tid = threadIdx.x;
    const float* p = fusion + (size_t)bc*HWc;
    float s=0.f, m=-3.4e38f;
    for (int i=tid;i<HWc;i+=256){ float v=p[i]; s+=v; m=fmaxf(m,v); }
    __shared__ float ss[256], sm[256];
    ss[tid]=s; sm[tid]=m;
    __syncthreads();
    for (int st=128; st>0; st>>=1){
        if (tid<st){ ss[tid]+=ss[tid+st]; sm[tid]=fmaxf(sm[tid],sm[tid+st]); }
        __syncthreads();
    }
    if (tid==0){ pavg[bc]=ss[0]*(1.0f/16384.0f); pmax[bc]=sm[0]; }
}

__global__ void mlp_kernel(const float* __restrict__ pavg, const float* __restrict__ pmax,
    const float* __restrict__ fc1, const float* __restrict__ fc2, float* __restrict__ ca)
{
    int b = blockIdx.x; int tid = threadIdx.x; // 64 threads
    __shared__ float hs[4];
    if (tid < 4){
        float sa_=0.f, sm_=0.f;
        for (int c=0;c<64;c++){
            float w = fc1[tid*64+c];
            sa_ = fmaf(w, pavg[b*64+c], sa_);
            sm_ = fmaf(w, pmax[b*64+c], sm_);
        }
        hs[tid] = fmaxf(sa_,0.f) + fmaxf(sm_,0.f);
    }
    __syncthreads();
    float o = 0.f;
    #pragma unroll
    for (int j=0;j<4;j++) o = fmaf(fc2[tid*4+j], hs[j], o);
    ca[b*64+tid] = 1.0f/(1.0f+expf(-o));
}

__global__ __launch_bounds__(256) void applyca_kernel(float* __restrict__ fusion,
    const float* __restrict__ ca, float* __restrict__ spmean, float* __restrict__ spmax)
{
    int idx = blockIdx.x*256+threadIdx.x;
    int b = idx>>14; int p = idx&16383;
    float s=0.f, m=-3.4e38f;
    float* fp = fusion + (size_t)b*64*HWc + p;
    const float* cp = ca + b*64;
    for (int c=0;c<64;c++){
        float v = fp[(size_t)c*HWc] * cp[c];
        fp[(size_t)c*HWc] = v;
        s += v; m = fmaxf(m, v);
    }
    spmean[idx] = s*(1.0f/64.0f);
    spmax[idx] = m;
}

__global__ __launch_bounds__(256) void spconv_kernel(const float* __restrict__ spmean,
    const float* __restrict__ spmax, const float* __restrict__ spw, float* __restrict__ sa)
{
    int idx = blockIdx.x*256+threadIdx.x;
    int b=idx>>14; int p=idx&16383;
    int i=p>>7, j=p&127;
    float acc=0.f;
    for (int k=0;k<49;k++){
        int ky=k/7-3, kx=k%7-3;
        int ii=i+ky, jj=j+kx;
        if (ii>=0&&ii<Hd&&jj>=0&&jj<Wd){
            int q = b*HWc + ii*Wd+jj;
            acc = fmaf(spw[k],    spmean[q], acc);
            acc = fmaf(spw[49+k], spmax[q], acc);
        }
    }
    sa[idx] = 1.0f/(1.0f+expf(-acc));
}

// ---------------------------------------------------------------------------
extern "C" void kernel_launch(void* const* d_in, const int* in_sizes, int n_in,
                              void* d_out, int out_size, void* d_ws, size_t ws_size,
                              hipStream_t stream)
{
    const float* x         = (const float*)d_in[0];
    const float* conv_in_w = (const float*)d_in[1];
    const float* bn1_g = (const float*)d_in[2];
    const float* bn1_b = (const float*)d_in[3];
    const float* bn1_m = (const float*)d_in[4];
    const float* bn1_v = (const float*)d_in[5];
    const float* down1_w = (const float*)d_in[6];
    const float* down1_b = (const float*)d_in[7];
    const float* down2_w = (const float*)d_in[8];
    const float* down2_b = (const float*)d_in[9];
    const float* wt_w = (const float*)d_in[10];
    const float* wt_b = (const float*)d_in[11];
    const float* edge_w = (const float*)d_in[12];
    const float* edge_b = (const float*)d_in[13];
    const float* up_w = (const float*)d_in[14];
    const float* bn2_g = (const float*)d_in[15];
    const float* bn2_b = (const float*)d_in[16];
    const float* bn2_m = (const float*)d_in[17];
    const float* bn2_v = (const float*)d_in[18];
    const float* combine_w = (const float*)d_in[19];
    const float* combine_b = (const float*)d_in[20];
    const float* fc1 = (const float*)d_in[21];
    const float* fc2 = (const float*)d_in[22];
    const float* spw = (const float*)d_in[23];
    const float* out_w = (const float*)d_in[24];
    const float* bn3_g = (const float*)d_in[25];
    const float* bn3_b = (const float*)d_in[26];
    const float* bn3_m = (const float*)d_in[27];
    const float* bn3_v = (const float*)d_in[28];
    float* out = (float*)d_out;
    float* ws = (float*)d_ws;

    // workspace layout (floats)
    float* x1      = ws;                     // 16*64*16384 = 16777216
    float* fusion1 = x1 + 16777216;
    float* fusion  = fusion1 + 16777216;
    float* z       = fusion + 16777216;      // 16*9*16384 = 2359296
    float* z1      = z + 2359296;
    float* xin     = z1 + 2359296;           // 262144
    float* cA      = xin + 262144;
    float* Ebuf    = cA + 262144;
    float* wtgab   = Ebuf + 262144;          // 16*2*16384 = 524288
    float* spmean  = wtgab + 524288;
    float* spmaxb  = spmean + 262144;
    float* sabuf   = spmaxb + 262144;
    float* pavg    = sabuf + 262144;         // 1024
    float* pmaxb   = pavg + 1024;
    float* cab     = pmaxb + 1024;

    dim3 cgrid(64, 16);
    // x1 = relu(bn1(conv_in(x)))
    conv3x3_bn_kernel<<<cgrid, 256, 0, stream>>>(x, conv_in_w, bn1_g,bn1_b,bn1_m,bn1_v, nullptr, x1, 64);
    // channel-contracted tap maps for down1/down2
    zmaps_kernel<<<1024, 256, 0, stream>>>(x1, down2_w, down1_w, z, z1);
    // x_in = conv(x1, down1_w) + b  (via z1 taps)
    xin_kernel<<<1024, 256, 0, stream>>>(z1, down1_b, xin);
    // X_in (fused upsample+conv) -> DWT -> cA, E
    dwt_kernel<<<1024, 256, 0, stream>>>(z, down2_b, cA, Ebuf);
    // wt and gab maps
    wtgab_kernel<<<1024, 256, 0, stream>>>(cA, xin, wt_w, wt_b, wtgab);
    // fusion1 = relu(bn2(conv(cat[wt,gab], up_w)))
    conv3x3_bn_kernel<<<cgrid, 256, 0, stream>>>(wtgab, up_w, bn2_g,bn2_b,bn2_m,bn2_v, nullptr, fusion1, 2);
    // fusion = conv(cat[fusion1, edge*(x1+1)], combine_w) + b   (edge fused)
    combine_kernel<<<cgrid, 256, 0, stream>>>(fusion1, Ebuf, x1, edge_w, edge_b, combine_w, combine_b, fusion);
    // CBAM channel attention
    pool_kernel<<<1024, 256, 0, stream>>>(fusion, pavg, pmaxb);
    mlp_kernel<<<16, 64, 0, stream>>>(pavg, pmaxb, fc1, fc2, cab);
    // apply ca in place + spatial mean/max
    applyca_kernel<<<1024, 256, 0, stream>>>(fusion, cab, spmean, spmaxb);
    // spatial attention map
    spconv_kernel<<<1024, 256, 0, stream>>>(spmean, spmaxb, spw, sabuf);
    // out = relu(bn3(conv(att, out_w))), att = fusion*ca*sa fused via samul
    conv3x3_bn_kernel<<<cgrid, 256, 0, stream>>>(fusion, out_w, bn3_g,bn3_b,bn3_m,bn3_v, sabuf, out, 64);
}

// Round 2
// 618.150 us; speedup vs baseline: 3.6681x; 3.6681x over previous
//
#include <hip/hip_runtime.h>
#include <math.h>

#define HWc 16384
#define Wd 128
#define Hd 128

typedef __attribute__((ext_vector_type(8))) _Float16 half8;
typedef __attribute__((ext_vector_type(4))) float f32x4;

// ---------------------------------------------------------------------------
// Weight fragment prep: OIHW fp32 -> f16 fragments laid out so a lane's
// A-fragment (A[m=oc(lane&15)][k=ci(quad*8+j)]) is one contiguous 16B load.
// Layout: [t(9)][kc(cin/32)][ot(4)][lane(64)][j(8)]
// ---------------------------------------------------------------------------
__global__ void prep_wfrag_kernel(const float* __restrict__ w,
                                  _Float16* __restrict__ wf, int cin)
{
    int total = cin * 576;  // 9*(cin/32)*4*64*8
    int idx = blockIdx.x * 256 + threadIdx.x;
    if (idx >= total) return;
    int KC = cin >> 5;
    int j = idx & 7;
    int lane = (idx >> 3) & 63;
    int rest = idx >> 9;       // (t*KC + kc)*4 + ot
    int ot = rest & 3;
    int rest2 = rest >> 2;     // t*KC + kc
    int kc = rest2 % KC;
    int t = rest2 / KC;
    int oc = ot * 16 + (lane & 15);
    int ci = kc * 32 + ((lane >> 4) << 3) + j;
    wf[idx] = (_Float16)w[((size_t)oc * cin + ci) * 9 + t];
}

// ---------------------------------------------------------------------------
// MFMA conv 64->64 3x3 + BN + ReLU, optional per-pixel input multiplier.
// Block: 256 thr = 4 waves; output tile 64 oc x (16x16 px).
// LDS input layout [g=ci/8][y(18)][x(18)][ci%8] f16 -> B-frag = 1 ds_read_b128.
// GEMM per tap t: D[oc][px] += W_t[oc][ci] * In[ci][px], K=64 (2 MFMA kchunks).
// ---------------------------------------------------------------------------
__global__ __launch_bounds__(256) void mfma_conv64_kernel(
    const float* __restrict__ in, const _Float16* __restrict__ wf,
    const float* __restrict__ bng, const float* __restrict__ bnb,
    const float* __restrict__ bnm, const float* __restrict__ bnv,
    const float* __restrict__ samul, float* __restrict__ out)
{
    __shared__ __align__(16) _Float16 slds[20736];  // 8*18*18*8
    __shared__ float sc[64], sh[64];
    int tid = threadIdx.x;
    int b = blockIdx.y;
    int tileid = blockIdx.x;
    int th = tileid >> 3, tw = tileid & 7;
    int h0 = th * 16 - 1, w0 = tw * 16 - 1;
    if (tid < 64) {
        float inv = rsqrtf(bnv[tid] + 1e-5f);
        float s = bng[tid] * inv;
        sc[tid] = s;
        sh[tid] = bnb[tid] - bnm[tid] * s;
    }
    const float* sp = samul ? (samul + (size_t)b * HWc) : nullptr;
    // stage: item i = (g, y, x); thread loads 8 consecutive ci, one b128 write
    for (int i = tid; i < 2592; i += 256) {
        int g = i / 324;
        int rem = i - g * 324;
        int y = rem / 18, x = rem - (rem / 18) * 18;
        int hh = h0 + y, ww = w0 + x;
        half8 hv;
        if (hh >= 0 && hh < Hd && ww >= 0 && ww < Wd) {
            const float* ip = in + ((size_t)b * 64 + g * 8) * HWc + hh * Wd + ww;
            float s = sp ? sp[hh * Wd + ww] : 1.0f;
            #pragma unroll
            for (int k = 0; k < 8; k++) hv[k] = (_Float16)(ip[(size_t)k * HWc] * s);
        } else {
            #pragma unroll
            for (int k = 0; k < 8; k++) hv[k] = (_Float16)0.f;
        }
        *(half8*)&slds[i * 8] = hv;
    }
    __syncthreads();
    int lane = tid & 63, wid = tid >> 6;
    int lq = lane >> 4, ln = lane & 15;
    int y0 = wid * 4;
    f32x4 acc[4][4];
    #pragma unroll
    for (int r = 0; r < 4; r++)
        #pragma unroll
        for (int ot = 0; ot < 4; ot++)
            #pragma unroll
            for (int q = 0; q < 4; q++) acc[r][ot][q] = 0.f;

    for (int t = 0; t < 9; t++) {
        int dy = t / 3, dx = t - (t / 3) * 3;
        #pragma unroll
        for (int kc = 0; kc < 2; kc++) {
            half8 bf[4];
            #pragma unroll
            for (int r = 0; r < 4; r++) {
                int off = (((kc * 4 + lq) * 324) + (y0 + r + dy) * 18 + (ln + dx)) * 8;
                bf[r] = *(const half8*)&slds[off];
            }
            #pragma unroll
            for (int ot = 0; ot < 4; ot++) {
                half8 af = *(const half8*)(wf + (size_t)(((t * 2 + kc) * 4 + ot) * 64 + lane) * 8);
                #pragma unroll
                for (int r = 0; r < 4; r++)
                    acc[r][ot] = __builtin_amdgcn_mfma_f32_16x16x32_f16(af, bf[r], acc[r][ot], 0, 0, 0);
            }
        }
    }
    // epilogue: D row m = lq*4+reg -> oc, col n = ln -> x
    #pragma unroll
    for (int r = 0; r < 4; r++) {
        int yy = th * 16 + y0 + r;
        #pragma unroll
        for (int ot = 0; ot < 4; ot++) {
            #pragma unroll
            for (int reg = 0; reg < 4; reg++) {
                int oc = ot * 16 + lq * 4 + reg;
                float v = fmaf(acc[r][ot][reg], sc[oc], sh[oc]);
                out[((size_t)b * 64 + oc) * HWc + yy * Wd + tw * 16 + ln] = fmaxf(v, 0.f);
            }
        }
    }
}

// ---------------------------------------------------------------------------
// MFMA combine conv: cat([fusion1, edge*(x1+1)]) (128 ci) -> 64 oc, +bias.
// Two LDS stagings (64 ci each); second half computed on the fly
// (edgeterm[c] = (conv3x3(E, edge_w[c]) + edge_b[c]) * (x1[c]+1)).
// ---------------------------------------------------------------------------
__global__ __launch_bounds__(256) void mfma_combine_kernel(
    const float* __restrict__ fusion1, const float* __restrict__ Ein,
    const float* __restrict__ x1,
    const float* __restrict__ edge_w, const float* __restrict__ edge_b,
    const _Float16* __restrict__ wf, const float* __restrict__ cb,
    float* __restrict__ out)
{
    __shared__ __align__(16) _Float16 slds[20736];
    __shared__ float e20[400];
    __shared__ float ew[576];
    __shared__ float ebl[64];
    __shared__ float cbl[64];
    int tid = threadIdx.x;
    int b = blockIdx.y;
    int tileid = blockIdx.x;
    int th = tileid >> 3, tw = tileid & 7;
    int h0 = th * 16 - 1, w0 = tw * 16 - 1;
    {
        const float* ep = Ein + (size_t)b * HWc;
        for (int i = tid; i < 400; i += 256) {
            int y = i / 20, x = i - (i / 20) * 20;
            int hh = h0 - 1 + y, ww = w0 - 1 + x;
            e20[i] = (hh >= 0 && hh < Hd && ww >= 0 && ww < Wd) ? ep[hh * Wd + ww] : 0.f;
        }
        for (int i = tid; i < 576; i += 256) ew[i] = edge_w[i];
        if (tid < 64) { ebl[tid] = edge_b[tid]; cbl[tid] = cb[tid]; }
    }
    int lane = tid & 63, wid = tid >> 6;
    int lq = lane >> 4, ln = lane & 15;
    int y0 = wid * 4;
    f32x4 acc[4][4];
    #pragma unroll
    for (int r = 0; r < 4; r++)
        #pragma unroll
        for (int ot = 0; ot < 4; ot++)
            #pragma unroll
            for (int q = 0; q < 4; q++) acc[r][ot][q] = 0.f;

    for (int h = 0; h < 2; h++) {
        __syncthreads();  // protect slds (and e20/ew on h==1) from prior reads
        if (h == 0) {
            for (int i = tid; i < 2592; i += 256) {
                int g = i / 324;
                int rem = i - g * 324;
                int y = rem / 18, x = rem - (rem / 18) * 18;
                int hh = h0 + y, ww = w0 + x;
                half8 hv;
                if (hh >= 0 && hh < Hd && ww >= 0 && ww < Wd) {
                    const float* ip = fusion1 + ((size_t)b * 64 + g * 8) * HWc + hh * Wd + ww;
                    #pragma unroll
                    for (int k = 0; k < 8; k++) hv[k] = (_Float16)ip[(size_t)k * HWc];
                } else {
                    #pragma unroll
                    for (int k = 0; k < 8; k++) hv[k] = (_Float16)0.f;
                }
                *(half8*)&slds[i * 8] = hv;
            }
        } else {
            for (int i = tid; i < 2592; i += 256) {
                int g = i / 324;
                int rem = i - g * 324;
                int y = rem / 18, x = rem - (rem / 18) * 18;
                int hh = h0 + y, ww = w0 + x;
                half8 hv;
                if (hh >= 0 && hh < Hd && ww >= 0 && ww < Wd) {
                    float e[9];
                    #pragma unroll
                    for (int tt = 0; tt < 9; tt++)
                        e[tt] = e20[(y + tt / 3) * 20 + x + (tt - (tt / 3) * 3)];
                    const float* xp = x1 + ((size_t)b * 64 + g * 8) * HWc + hh * Wd + ww;
                    #pragma unroll
                    for (int k = 0; k < 8; k++) {
                        int c = g * 8 + k;
                        float ec = ebl[c];
                        #pragma unroll
                        for (int tt = 0; tt < 9; tt++) ec = fmaf(ew[c * 9 + tt], e[tt], ec);
                        hv[k] = (_Float16)(ec * (xp[(size_t)k * HWc] + 1.0f));
                    }
                } else {
                    #pragma unroll
                    for (int k = 0; k < 8; k++) hv[k] = (_Float16)0.f;
                }
                *(half8*)&slds[i * 8] = hv;
            }
        }
        __syncthreads();
        for (int t = 0; t < 9; t++) {
            int dy = t / 3, dx = t - (t / 3) * 3;
            #pragma unroll
            for (int kc = 0; kc < 2; kc++) {
                int kcg = h * 2 + kc;
                half8 bf[4];
                #pragma unroll
                for (int r = 0; r < 4; r++) {
                    int off = (((kc * 4 + lq) * 324) + (y0 + r + dy) * 18 + (ln + dx)) * 8;
                    bf[r] = *(const half8*)&slds[off];
                }
                #pragma unroll
                for (int ot = 0; ot < 4; ot++) {
                    half8 af = *(const half8*)(wf + (size_t)(((t * 4 + kcg) * 4 + ot) * 64 + lane) * 8);
                    #pragma unroll
                    for (int r = 0; r < 4; r++)
                        acc[r][ot] = __builtin_amdgcn_mfma_f32_16x16x32_f16(af, bf[r], acc[r][ot], 0, 0, 0);
                }
            }
        }
    }
    #pragma unroll
    for (int r = 0; r < 4; r++) {
        int yy = th * 16 + y0 + r;
        #pragma unroll
        for (int ot = 0; ot < 4; ot++) {
            #pragma unroll
            for (int reg = 0; reg < 4; reg++) {
                int oc = ot * 16 + lq * 4 + reg;
                out[((size_t)b * 64 + oc) * HWc + yy * Wd + tw * 16 + ln] =
                    acc[r][ot][reg] + cbl[oc];
            }
        }
    }
}

// ---------------------------------------------------------------------------
// Scalar 3x3 conv + BN + ReLU for tiny cin (used for up_w conv, cin=2).
// ---------------------------------------------------------------------------
__global__ __launch_bounds__(256) void conv3x3_bn_kernel(
    const float* __restrict__ in, const float* __restrict__ wgt,
    const float* __restrict__ bng, const float* __restrict__ bnb,
    const float* __restrict__ bnm, const float* __restrict__ bnv,
    float* __restrict__ out, int cin)
{
    __shared__ float tile[18*18];
    __shared__ float wl[576];
    __shared__ float sc[64], sh[64];
    int tid = threadIdx.x;
    int tileid = blockIdx.x; int b = blockIdx.y;
    int th = tileid >> 3, tw = tileid & 7;
    int h0 = th*16 - 1, w0 = tw*16 - 1;
    if (tid < 64) {
        float inv = rsqrtf(bnv[tid] + 1e-5f);
        float s = bng[tid]*inv;
        sc[tid] = s;
        sh[tid] = bnb[tid] - bnm[tid]*s;
    }
    float acc[64];
    #pragma unroll
    for (int i=0;i<64;i++) acc[i]=0.f;
    int py = tid>>4, px = tid&15;
    for (int ci=0; ci<cin; ci++){
        __syncthreads();
        const float* inp = in + ((size_t)b*cin + ci)*HWc;
        for (int i = tid; i < 324; i += 256) {
            int y=i/18, x=i%18; int hh=h0+y, ww=w0+x;
            tile[i] = (hh>=0&&hh<Hd&&ww>=0&&ww<Wd) ? inp[hh*Wd+ww] : 0.f;
        }
        for (int i = tid; i < 576; i += 256) {
            int oc = i/9, t = i - oc*9;
            wl[i] = wgt[((size_t)oc*cin + ci)*9 + t];
        }
        __syncthreads();
        float v[9];
        #pragma unroll
        for (int dy=0;dy<3;dy++)
            #pragma unroll
            for (int dx=0;dx<3;dx++)
                v[dy*3+dx] = tile[(py+dy)*18 + px+dx];
        #pragma unroll
        for (int oc=0;oc<64;oc++){
            float a = acc[oc];
            #pragma unroll
            for (int t=0;t<9;t++) a = fmaf(wl[oc*9+t], v[t], a);
            acc[oc]=a;
        }
    }
    int hh = h0+1+py, ww = w0+1+px;
    size_t base = (size_t)b*64*HWc + hh*Wd + ww;
    #pragma unroll
    for (int oc=0;oc<64;oc++){
        float y = fmaf(acc[oc], sc[oc], sh[oc]);
        out[base + (size_t)oc*HWc] = fmaxf(y, 0.f);
    }
}

// ---------------------------------------------------------------------------
// z maps: z_t = sum_c down2_w[c,t]*x1[c] (and z1 for down1).
// ---------------------------------------------------------------------------
__global__ __launch_bounds__(256) void zmaps_kernel(const float* __restrict__ x1,
    const float* __restrict__ w2, const float* __restrict__ w1,
    float* __restrict__ z, float* __restrict__ z1)
{
    int idx = blockIdx.x*256 + threadIdx.x;
    int b = idx >> 14; int p = idx & 16383;
    const float* xp = x1 + (size_t)b*64*HWc + p;
    float a2[9], a1[9];
    #pragma unroll
    for (int t=0;t<9;t++){ a2[t]=0.f; a1[t]=0.f; }
    for (int c=0;c<64;c++){
        float v = xp[(size_t)c*HWc];
        #pragma unroll
        for (int t=0;t<9;t++){
            a2[t] = fmaf(w2[c*9+t], v, a2[t]);
            a1[t] = fmaf(w1[c*9+t], v, a1[t]);
        }
    }
    #pragma unroll
    for (int t=0;t<9;t++){
        z [((size_t)b*9+t)*HWc + p] = a2[t];
        z1[((size_t)b*9+t)*HWc + p] = a1[t];
    }
}

__global__ __launch_bounds__(256) void xin_kernel(const float* __restrict__ z1,
    const float* __restrict__ b1p, float* __restrict__ xin)
{
    int idx = blockIdx.x*256+threadIdx.x;
    int b=idx>>14; int p=idx&16383;
    int i=p>>7, j=p&127;
    float acc = b1p[0];
    #pragma unroll
    for (int t=0;t<9;t++){
        int ii=i+t/3-1, jj=j+t%3-1;
        if (ii>=0&&ii<Hd&&jj>=0&&jj<Wd)
            acc += z1[((size_t)b*9+t)*HWc + ii*Wd+jj];
    }
    xin[idx]=acc;
}

// ---------------------------------------------------------------------------
// Fused upsample+conv -> Haar DWT -> cA, E
// ---------------------------------------------------------------------------
__global__ __launch_bounds__(256) void dwt_kernel(const float* __restrict__ z,
    const float* __restrict__ b2p, float* __restrict__ cA, float* __restrict__ Eo)
{
    int idx = blockIdx.x*256 + threadIdx.x;
    int b = idx >> 14; int p = idx & 16383;
    int u = p >> 7, v = p & 127;
    float b2 = b2p[0];
    int rlo[4], rhi[4]; float rf[4]; bool rv[4];
    int clo[4], chi[4]; float cf[4]; bool cvv[4];
    #pragma unroll
    for (int k=0;k<4;k++){
        int r = 2*u - 1 + k;
        rv[k] = (r>=0 && r<256);
        int rr = rv[k] ? r : 0;
        float cc = ((float)rr * 127.0f) / 255.0f;
        int lo = (int)cc;
        rlo[k]=lo; rhi[k]=min(lo+1,127); rf[k]=cc-(float)lo;
        int s = 2*v - 1 + k;
        cvv[k] = (s>=0 && s<256);
        int ss = cvv[k] ? s : 0;
        float c2 = ((float)ss * 127.0f) / 255.0f;
        int lo2=(int)c2;
        clo[k]=lo2; chi[k]=min(lo2+1,127); cf[k]=c2-(float)lo2;
    }
    float Xin[4] = {b2,b2,b2,b2};
    #pragma unroll
    for (int t=0;t<9;t++){
        int dy=t/3, dx=t%3;
        const float* zp = z + ((size_t)b*9 + t)*HWc;
        #pragma unroll
        for (int e=0;e<4;e++){
            int ey=e>>1, ex=e&1;
            int k=ey+dy, l=ex+dx;
            if (rv[k] && cvv[l]){
                const float* row0 = zp + rlo[k]*Wd;
                const float* row1 = zp + rhi[k]*Wd;
                float v00=row0[clo[l]], v01=row0[chi[l]];
                float v10=row1[clo[l]], v11=row1[chi[l]];
                float fc_=cf[l], fr_=rf[k];
                float top = v00*(1.0f-fc_) + v01*fc_;
                float bot = v10*(1.0f-fc_) + v11*fc_;
                Xin[e] += top*(1.0f-fr_) + bot*fr_;
            }
        }
    }
    float a=Xin[0], bb=Xin[1], c_=Xin[2], d_=Xin[3];
    float LL=0.5f*( a+bb+c_+d_);
    float LH=0.5f*(-a-bb+c_+d_);
    float HL=0.5f*(-a+bb-c_+d_);
    float HH=0.5f*( a-bb-c_+d_);
    cA[(size_t)b*HWc + p] = LL;
    Eo[(size_t)b*HWc + p] = fabsf(LH)+fabsf(HL)+fabsf(HH);
}

__global__ __launch_bounds__(256) void wtgab_kernel(const float* __restrict__ cA,
    const float* __restrict__ xin, const float* __restrict__ wtw, const float* __restrict__ wtb,
    float* __restrict__ wtgab)
{
    __shared__ float gm[49];
    int tid=threadIdx.x;
    if (tid<49){
        int ky=tid/7, kx=tid%7;
        float yy=(float)(ky-3), xx=(float)(kx-3);
        float s=0.f;
        for (int t=0;t<4;t++){
            float theta = (float)t * 0.7853981633974483f;
            float ct=cosf(theta), st=sinf(theta);
            float xt = xx*ct + yy*st;
            float yt = -xx*st + yy*ct;
            s += expf(-0.5f*(xt*xt*(1.0f/16.0f) + yt*yt*(1.0f/64.0f))) * cosf(0.6283185307179586f*xt);
        }
        gm[tid]=0.25f*s;
    }
    __syncthreads();
    int idx = blockIdx.x*256+tid;
    int b=idx>>14; int p=idx&16383;
    int i=p>>7, j=p&127;
    float wacc = wtb[0];
    #pragma unroll
    for (int t=0;t<9;t++){
        int ii=i+t/3-1, jj=j+t%3-1;
        if (ii>=0&&ii<Hd&&jj>=0&&jj<Wd)
            wacc = fmaf(wtw[t], cA[b*HWc + ii*Wd+jj], wacc);
    }
    float g=0.f;
    for (int k=0;k<49;k++){
        int ii=i+k/7-3, jj=j+k%7-3;
        if (ii>=0&&ii<Hd&&jj>=0&&jj<Wd)
            g = fmaf(gm[k], xin[b*HWc + ii*Wd+jj], g);
    }
    wtgab[((size_t)b*2)*HWc + p] = wacc;
    wtgab[((size_t)b*2+1)*HWc + p] = 1.0f/(1.0f+expf(-g));
}

__global__ __launch_bounds__(256) void pool_kernel(const float* __restrict__ fusion,
    float* __restrict__ pavg, float* __restrict__ pmax)
{
    int bc = blockIdx.x; int tid = threadIdx.x;
    const float* p = fusion + (size_t)bc*HWc;
    float s=0.f, m=-3.4e38f;
    for (int i=tid;i<HWc;i+=256){ float v=p[i]; s+=v; m=fmaxf(m,v); }
    __shared__ float ss[256], sm[256];
    ss[tid]=s; sm[tid]=m;
    __syncthreads();
    for (int st=128; st>0; st>>=1){
        if (tid<st){ ss[tid]+=ss[tid+st]; sm[tid]=fmaxf(sm[tid],sm[tid+st]); }
        __syncthreads();
    }
    if (tid==0){ pavg[bc]=ss[0]*(1.0f/16384.0f); pmax[bc]=sm[0]; }
}

__global__ void mlp_kernel(const float* __restrict__ pavg, const float* __restrict__ pmax,
    const float* __restrict__ fc1, const float* __restrict__ fc2, float* __restrict__ ca)
{
    int b = blockIdx.x; int tid = threadIdx.x; // 64 threads
    __shared__ float hs[4];
    if (tid < 4){
        float sa_=0.f, sm_=0.f;
        for (int c=0;c<64;c++){
            float w = fc1[tid*64+c];
            sa_ = fmaf(w, pavg[b*64+c], sa_);
            sm_ = fmaf(w, pmax[b*64+c], sm_);
        }
        hs[tid] = fmaxf(sa_,0.f) + fmaxf(sm_,0.f);
    }
    __syncthreads();
    float o = 0.f;
    #pragma unroll
    for (int j=0;j<4;j++) o = fmaf(fc2[tid*4+j], hs[j], o);
    ca[b*64+tid] = 1.0f/(1.0f+expf(-o));
}

__global__ __launch_bounds__(256) void applyca_kernel(float* __restrict__ fusion,
    const float* __restrict__ ca, float* __restrict__ spmean, float* __restrict__ spmax)
{
    int idx = blockIdx.x*256+threadIdx.x;
    int b = idx>>14; int p = idx&16383;
    float s=0.f, m=-3.4e38f;
    float* fp = fusion + (size_t)b*64*HWc + p;
    const float* cp = ca + b*64;
    for (int c=0;c<64;c++){
        float v = fp[(size_t)c*HWc] * cp[c];
        fp[(size_t)c*HWc] = v;
        s += v; m = fmaxf(m, v);
    }
    spmean[idx] = s*(1.0f/64.0f);
    spmax[idx] = m;
}

__global__ __launch_bounds__(256) void spconv_kernel(const float* __restrict__ spmean,
    const float* __restrict__ spmax, const float* __restrict__ spw, float* __restrict__ sa)
{
    int idx = blockIdx.x*256+threadIdx.x;
    int b=idx>>14; int p=idx&16383;
    int i=p>>7, j=p&127;
    float acc=0.f;
    for (int k=0;k<49;k++){
        int ky=k/7-3, kx=k%7-3;
        int ii=i+ky, jj=j+kx;
        if (ii>=0&&ii<Hd&&jj>=0&&jj<Wd){
            int q = b*HWc + ii*Wd+jj;
            acc = fmaf(spw[k],    spmean[q], acc);
            acc = fmaf(spw[49+k], spmax[q], acc);
        }
    }
    sa[idx] = 1.0f/(1.0f+expf(-acc));
}

// ---------------------------------------------------------------------------
extern "C" void kernel_launch(void* const* d_in, const int* in_sizes, int n_in,
                              void* d_out, int out_size, void* d_ws, size_t ws_size,
                              hipStream_t stream)
{
    const float* x         = (const float*)d_in[0];
    const float* conv_in_w = (const float*)d_in[1];
    const float* bn1_g = (const float*)d_in[2];
    const float* bn1_b = (const float*)d_in[3];
    const float* bn1_m = (const float*)d_in[4];
    const float* bn1_v = (const float*)d_in[5];
    const float* down1_w = (const float*)d_in[6];
    const float* down1_b = (const float*)d_in[7];
    const float* down2_w = (const float*)d_in[8];
    const float* down2_b = (const float*)d_in[9];
    const float* wt_w = (const float*)d_in[10];
    const float* wt_b = (const float*)d_in[11];
    const float* edge_w = (const float*)d_in[12];
    const float* edge_b = (const float*)d_in[13];
    const float* up_w = (const float*)d_in[14];
    const float* bn2_g = (const float*)d_in[15];
    const float* bn2_b = (const float*)d_in[16];
    const float* bn2_m = (const float*)d_in[17];
    const float* bn2_v = (const float*)d_in[18];
    const float* combine_w = (const float*)d_in[19];
    const float* combine_b = (const float*)d_in[20];
    const float* fc1 = (const float*)d_in[21];
    const float* fc2 = (const float*)d_in[22];
    const float* spw = (const float*)d_in[23];
    const float* out_w = (const float*)d_in[24];
    const float* bn3_g = (const float*)d_in[25];
    const float* bn3_b = (const float*)d_in[26];
    const float* bn3_m = (const float*)d_in[27];
    const float* bn3_v = (const float*)d_in[28];
    float* out = (float*)d_out;
    float* ws = (float*)d_ws;

    // workspace layout (floats)
    float* x1      = ws;                     // 16*64*16384
    float* fusion1 = x1 + 16777216;
    float* fusion  = fusion1 + 16777216;
    float* z       = fusion + 16777216;      // 16*9*16384
    float* z1      = z + 2359296;
    float* xin     = z1 + 2359296;           // 262144
    float* cA      = xin + 262144;
    float* Ebuf    = cA + 262144;
    float* wtgab   = Ebuf + 262144;          // 16*2*16384
    float* spmean  = wtgab + 524288;
    float* spmaxb  = spmean + 262144;
    float* sabuf   = spmaxb + 262144;
    float* pavg    = sabuf + 262144;
    float* pmaxb   = pavg + 1024;
    float* cab     = pmaxb + 1024;
    // f16 weight-fragment buffers
    _Float16* wf_in   = (_Float16*)(cab + 1024);       // 36864 f16
    _Float16* wf_out  = wf_in + 36864;                 // 36864 f16
    _Float16* wf_comb = wf_out + 36864;                // 73728 f16

    // weight fragment prep
    prep_wfrag_kernel<<<144, 256, 0, stream>>>(conv_in_w, wf_in, 64);
    prep_wfrag_kernel<<<144, 256, 0, stream>>>(out_w, wf_out, 64);
    prep_wfrag_kernel<<<288, 256, 0, stream>>>(combine_w, wf_comb, 128);

    dim3 cgrid(64, 16);
    // x1 = relu(bn1(conv_in(x)))
    mfma_conv64_kernel<<<cgrid, 256, 0, stream>>>(x, wf_in, bn1_g,bn1_b,bn1_m,bn1_v, nullptr, x1);
    // channel-contracted tap maps for down1/down2
    zmaps_kernel<<<1024, 256, 0, stream>>>(x1, down2_w, down1_w, z, z1);
    // x_in = conv(x1, down1_w) + b
    xin_kernel<<<1024, 256, 0, stream>>>(z1, down1_b, xin);
    // fused upsample+conv -> DWT -> cA, E
    dwt_kernel<<<1024, 256, 0, stream>>>(z, down2_b, cA, Ebuf);
    // wt and gab maps
    wtgab_kernel<<<1024, 256, 0, stream>>>(cA, xin, wt_w, wt_b, wtgab);
    // fusion1 = relu(bn2(conv(cat[wt,gab], up_w)))  (cin=2, scalar kernel)
    conv3x3_bn_kernel<<<cgrid, 256, 0, stream>>>(wtgab, up_w, bn2_g,bn2_b,bn2_m,bn2_v, fusion1, 2);
    // fusion = conv(cat[fusion1, edge*(x1+1)], combine_w) + b
    mfma_combine_kernel<<<cgrid, 256, 0, stream>>>(fusion1, Ebuf, x1, edge_w, edge_b, wf_comb, combine_b, fusion);
    // CBAM
    pool_kernel<<<1024, 256, 0, stream>>>(fusion, pavg, pmaxb);
    mlp_kernel<<<16, 64, 0, stream>>>(pavg, pmaxb, fc1, fc2, cab);
    applyca_kernel<<<1024, 256, 0, stream>>>(fusion, cab, spmean, spmaxb);
    spconv_kernel<<<1024, 256, 0, stream>>>(spmean, spmaxb, spw, sabuf);
    // out = relu(bn3(conv(fusion*ca*sa, out_w)))
    mfma_conv64_kernel<<<cgrid, 256, 0, stream>>>(fusion, wf_out, bn3_g,bn3_b,bn3_m,bn3_v, sabuf, out);
}

// Round 3
// 537.342 us; speedup vs baseline: 4.2197x; 1.1504x over previous
//
#include <hip/hip_runtime.h>
#include <math.h>

#define HWc 16384
#define Wd 128
#define Hd 128

typedef __attribute__((ext_vector_type(8))) _Float16 half8;
typedef __attribute__((ext_vector_type(4))) _Float16 half4;
typedef __attribute__((ext_vector_type(4))) float f32x4;

// ---------------------------------------------------------------------------
// Weight fragment prep: OIHW fp32 -> f16 fragments.
// Layout: [t(9)][kc(cin/32)][ot(4)][lane(64)][j(8)]
// ---------------------------------------------------------------------------
__global__ void prep_wfrag_kernel(const float* __restrict__ w,
                                  _Float16* __restrict__ wf, int cin)
{
    int total = cin * 576;
    int idx = blockIdx.x * 256 + threadIdx.x;
    if (idx >= total) return;
    int KC = cin >> 5;
    int j = idx & 7;
    int lane = (idx >> 3) & 63;
    int rest = idx >> 9;
    int ot = rest & 3;
    int rest2 = rest >> 2;
    int kc = rest2 % KC;
    int t = rest2 / KC;
    int oc = ot * 16 + (lane & 15);
    int ci = kc * 32 + ((lane >> 4) << 3) + j;
    wf[idx] = (_Float16)w[((size_t)oc * cin + ci) * 9 + t];
}

// ---------------------------------------------------------------------------
// NCHW fp32 -> pack4 f16:  out[((b*16+g4)*HW + p)*4 + k] = in[b, g4*4+k, p]
// ---------------------------------------------------------------------------
__global__ __launch_bounds__(256) void pack4_kernel(const float* __restrict__ in,
                                                    _Float16* __restrict__ outp)
{
    int idx = blockIdx.x * 256 + threadIdx.x;
    int b = idx >> 14, p = idx & 16383;
    #pragma unroll
    for (int g4 = 0; g4 < 16; g4++) {
        half4 v;
        #pragma unroll
        for (int k = 0; k < 4; k++)
            v[k] = (_Float16)in[((size_t)b * 64 + g4 * 4 + k) * HWc + p];
        *(half4*)&outp[(((size_t)b * 16 + g4) * HWc + p) * 4] = v;
    }
}

// ---------------------------------------------------------------------------
// MFMA conv 64->64 3x3 (+BN+ReLU). Input pack4 f16. Optional per-pixel (samul)
// and per-channel (camul) input multipliers. Output: pack4 f16 OR fp32 NCHW.
// ---------------------------------------------------------------------------
__global__ __launch_bounds__(256) void mfma_conv64_kernel(
    const _Float16* __restrict__ inp4, const _Float16* __restrict__ wf,
    const float* __restrict__ bng, const float* __restrict__ bnb,
    const float* __restrict__ bnm, const float* __restrict__ bnv,
    const float* __restrict__ samul, const float* __restrict__ camul,
    _Float16* __restrict__ outp4, float* __restrict__ out32)
{
    __shared__ __align__(16) _Float16 slds[20736];  // [g(8)][y(18)][x(18)][8]
    __shared__ float sc[64], sh[64], caf[64];
    __shared__ float satile[324];
    int tid = threadIdx.x;
    int b = blockIdx.y;
    int tileid = blockIdx.x;
    int th = tileid >> 3, tw = tileid & 7;
    int h0 = th * 16 - 1, w0 = tw * 16 - 1;
    if (tid < 64) {
        float inv = rsqrtf(bnv[tid] + 1e-5f);
        float s = bng[tid] * inv;
        sc[tid] = s;
        sh[tid] = bnb[tid] - bnm[tid] * s;
        caf[tid] = camul ? camul[b * 64 + tid] : 1.0f;
    }
    if (samul) {
        const float* sp = samul + (size_t)b * HWc;
        for (int i = tid; i < 324; i += 256) {
            int y = i / 18, x = i - (i / 18) * 18;
            int hh = h0 + y, ww = w0 + x;
            satile[i] = (hh >= 0 && hh < Hd && ww >= 0 && ww < Wd) ? sp[hh * Wd + ww] : 0.f;
        }
    }
    __syncthreads();  // caf/satile ready before staging uses them
    const _Float16* ib = inp4 + (size_t)b * 16 * HWc * 4;
    for (int i = tid; i < 2592; i += 256) {
        int g = i / 324;
        int rem = i - g * 324;
        int y = rem / 18, x = rem - (rem / 18) * 18;
        int hh = h0 + y, ww = w0 + x;
        half8 hv;
        if (hh >= 0 && hh < Hd && ww >= 0 && ww < Wd) {
            int p = hh * Wd + ww;
            half4 a = *(const half4*)&ib[((size_t)(2 * g) * HWc + p) * 4];
            half4 c = *(const half4*)&ib[((size_t)(2 * g + 1) * HWc + p) * 4];
            if (samul) {
                float m = satile[y * 18 + x];
                #pragma unroll
                for (int k = 0; k < 4; k++) {
                    hv[k]     = (_Float16)((float)a[k] * caf[g * 8 + k] * m);
                    hv[k + 4] = (_Float16)((float)c[k] * caf[g * 8 + 4 + k] * m);
                }
            } else {
                #pragma unroll
                for (int k = 0; k < 4; k++) { hv[k] = a[k]; hv[k + 4] = c[k]; }
            }
        } else {
            #pragma unroll
            for (int k = 0; k < 8; k++) hv[k] = (_Float16)0.f;
        }
        *(half8*)&slds[i * 8] = hv;
    }
    __syncthreads();
    int lane = tid & 63, wid = tid >> 6;
    int lq = lane >> 4, ln = lane & 15;
    int y0 = wid * 4;
    f32x4 acc[4][4];
    #pragma unroll
    for (int r = 0; r < 4; r++)
        #pragma unroll
        for (int ot = 0; ot < 4; ot++)
            #pragma unroll
            for (int q = 0; q < 4; q++) acc[r][ot][q] = 0.f;

    for (int t = 0; t < 9; t++) {
        int dy = t / 3, dx = t - (t / 3) * 3;
        #pragma unroll
        for (int kc = 0; kc < 2; kc++) {
            half8 bf[4];
            #pragma unroll
            for (int r = 0; r < 4; r++) {
                int off = (((kc * 4 + lq) * 324) + (y0 + r + dy) * 18 + (ln + dx)) * 8;
                bf[r] = *(const half8*)&slds[off];
            }
            #pragma unroll
            for (int ot = 0; ot < 4; ot++) {
                half8 af = *(const half8*)(wf + (size_t)(((t * 2 + kc) * 4 + ot) * 64 + lane) * 8);
                #pragma unroll
                for (int r = 0; r < 4; r++)
                    acc[r][ot] = __builtin_amdgcn_mfma_f32_16x16x32_f16(af, bf[r], acc[r][ot], 0, 0, 0);
            }
        }
    }
    // epilogue: oc = ot*16 + lq*4 + reg = (ot*4+lq)*4 + reg
    #pragma unroll
    for (int r = 0; r < 4; r++) {
        int yy = th * 16 + y0 + r;
        int p = yy * Wd + tw * 16 + ln;
        #pragma unroll
        for (int ot = 0; ot < 4; ot++) {
            int g4 = ot * 4 + lq;
            if (out32) {
                #pragma unroll
                for (int reg = 0; reg < 4; reg++) {
                    int oc = g4 * 4 + reg;
                    float v = fmaf(acc[r][ot][reg], sc[oc], sh[oc]);
                    out32[((size_t)b * 64 + oc) * HWc + p] = fmaxf(v, 0.f);
                }
            } else {
                half4 hv;
                #pragma unroll
                for (int reg = 0; reg < 4; reg++) {
                    int oc = g4 * 4 + reg;
                    float v = fmaf(acc[r][ot][reg], sc[oc], sh[oc]);
                    hv[reg] = (_Float16)fmaxf(v, 0.f);
                }
                *(half4*)&outp4[(((size_t)b * 16 + g4) * HWc + p) * 4] = hv;
            }
        }
    }
}

// ---------------------------------------------------------------------------
// MFMA combine conv: cat([fusion1, edge*(x1+1)]) (128 ci) -> 64 oc, +bias.
// Inputs pack4 f16; output pack4 f16.
// ---------------------------------------------------------------------------
__global__ __launch_bounds__(256) void mfma_combine_kernel(
    const _Float16* __restrict__ f1p, const float* __restrict__ Ein,
    const _Float16* __restrict__ x1p,
    const float* __restrict__ edge_w, const float* __restrict__ edge_b,
    const _Float16* __restrict__ wf, const float* __restrict__ cb,
    _Float16* __restrict__ outp4)
{
    __shared__ __align__(16) _Float16 slds[20736];
    __shared__ float e20[400];
    __shared__ float ew[576];
    __shared__ float ebl[64];
    __shared__ float cbl[64];
    int tid = threadIdx.x;
    int b = blockIdx.y;
    int tileid = blockIdx.x;
    int th = tileid >> 3, tw = tileid & 7;
    int h0 = th * 16 - 1, w0 = tw * 16 - 1;
    {
        const float* ep = Ein + (size_t)b * HWc;
        for (int i = tid; i < 400; i += 256) {
            int y = i / 20, x = i - (i / 20) * 20;
            int hh = h0 - 1 + y, ww = w0 - 1 + x;
            e20[i] = (hh >= 0 && hh < Hd && ww >= 0 && ww < Wd) ? ep[hh * Wd + ww] : 0.f;
        }
        for (int i = tid; i < 576; i += 256) ew[i] = edge_w[i];
        if (tid < 64) { ebl[tid] = edge_b[tid]; cbl[tid] = cb[tid]; }
    }
    int lane = tid & 63, wid = tid >> 6;
    int lq = lane >> 4, ln = lane & 15;
    int y0 = wid * 4;
    f32x4 acc[4][4];
    #pragma unroll
    for (int r = 0; r < 4; r++)
        #pragma unroll
        for (int ot = 0; ot < 4; ot++)
            #pragma unroll
            for (int q = 0; q < 4; q++) acc[r][ot][q] = 0.f;

    const _Float16* f1b = f1p + (size_t)b * 16 * HWc * 4;
    const _Float16* x1b = x1p + (size_t)b * 16 * HWc * 4;
    for (int h = 0; h < 2; h++) {
        __syncthreads();
        if (h == 0) {
            for (int i = tid; i < 2592; i += 256) {
                int g = i / 324;
                int rem = i - g * 324;
                int y = rem / 18, x = rem - (rem / 18) * 18;
                int hh = h0 + y, ww = w0 + x;
                half8 hv;
                if (hh >= 0 && hh < Hd && ww >= 0 && ww < Wd) {
                    int p = hh * Wd + ww;
                    half4 a = *(const half4*)&f1b[((size_t)(2 * g) * HWc + p) * 4];
                    half4 c = *(const half4*)&f1b[((size_t)(2 * g + 1) * HWc + p) * 4];
                    #pragma unroll
                    for (int k = 0; k < 4; k++) { hv[k] = a[k]; hv[k + 4] = c[k]; }
                } else {
                    #pragma unroll
                    for (int k = 0; k < 8; k++) hv[k] = (_Float16)0.f;
                }
                *(half8*)&slds[i * 8] = hv;
            }
        } else {
            for (int i = tid; i < 2592; i += 256) {
                int g = i / 324;
                int rem = i - g * 324;
                int y = rem / 18, x = rem - (rem / 18) * 18;
                int hh = h0 + y, ww = w0 + x;
                half8 hv;
                if (hh >= 0 && hh < Hd && ww >= 0 && ww < Wd) {
                    int p = hh * Wd + ww;
                    float e[9];
                    #pragma unroll
                    for (int tt = 0; tt < 9; tt++)
                        e[tt] = e20[(y + tt / 3) * 20 + x + (tt - (tt / 3) * 3)];
                    half4 a = *(const half4*)&x1b[((size_t)(2 * g) * HWc + p) * 4];
                    half4 c = *(const half4*)&x1b[((size_t)(2 * g + 1) * HWc + p) * 4];
                    #pragma unroll
                    for (int k = 0; k < 8; k++) {
                        int cc = g * 8 + k;
                        float ec = ebl[cc];
                        #pragma unroll
                        for (int tt = 0; tt < 9; tt++) ec = fmaf(ew[cc * 9 + tt], e[tt], ec);
                        float xv = (k < 4) ? (float)a[k] : (float)c[k - 4];
                        hv[k] = (_Float16)(ec * (xv + 1.0f));
                    }
                } else {
                    #pragma unroll
                    for (int k = 0; k < 8; k++) hv[k] = (_Float16)0.f;
                }
                *(half8*)&slds[i * 8] = hv;
            }
        }
        __syncthreads();
        for (int t = 0; t < 9; t++) {
            int dy = t / 3, dx = t - (t / 3) * 3;
            #pragma unroll
            for (int kc = 0; kc < 2; kc++) {
                int kcg = h * 2 + kc;
                half8 bf[4];
                #pragma unroll
                for (int r = 0; r < 4; r++) {
                    int off = (((kc * 4 + lq) * 324) + (y0 + r + dy) * 18 + (ln + dx)) * 8;
                    bf[r] = *(const half8*)&slds[off];
                }
                #pragma unroll
                for (int ot = 0; ot < 4; ot++) {
                    half8 af = *(const half8*)(wf + (size_t)(((t * 4 + kcg) * 4 + ot) * 64 + lane) * 8);
                    #pragma unroll
                    for (int r = 0; r < 4; r++)
                        acc[r][ot] = __builtin_amdgcn_mfma_f32_16x16x32_f16(af, bf[r], acc[r][ot], 0, 0, 0);
                }
            }
        }
    }
    #pragma unroll
    for (int r = 0; r < 4; r++) {
        int yy = th * 16 + y0 + r;
        int p = yy * Wd + tw * 16 + ln;
        #pragma unroll
        for (int ot = 0; ot < 4; ot++) {
            int g4 = ot * 4 + lq;
            half4 hv;
            #pragma unroll
            for (int reg = 0; reg < 4; reg++) {
                int oc = g4 * 4 + reg;
                hv[reg] = (_Float16)(acc[r][ot][reg] + cbl[oc]);
            }
            *(half4*)&outp4[(((size_t)b * 16 + g4) * HWc + p) * 4] = hv;
        }
    }
}

// ---------------------------------------------------------------------------
// Scalar 3x3 conv + BN + ReLU, tiny cin (up_w conv, cin=2). Output pack4 f16.
// ---------------------------------------------------------------------------
__global__ __launch_bounds__(256) void conv3x3_bn_kernel(
    const float* __restrict__ in, const float* __restrict__ wgt,
    const float* __restrict__ bng, const float* __restrict__ bnb,
    const float* __restrict__ bnm, const float* __restrict__ bnv,
    _Float16* __restrict__ outp4, int cin)
{
    __shared__ float tile[18*18];
    __shared__ float wl[576];
    __shared__ float sc[64], sh[64];
    int tid = threadIdx.x;
    int tileid = blockIdx.x; int b = blockIdx.y;
    int th = tileid >> 3, tw = tileid & 7;
    int h0 = th*16 - 1, w0 = tw*16 - 1;
    if (tid < 64) {
        float inv = rsqrtf(bnv[tid] + 1e-5f);
        float s = bng[tid]*inv;
        sc[tid] = s;
        sh[tid] = bnb[tid] - bnm[tid]*s;
    }
    float acc[64];
    #pragma unroll
    for (int i=0;i<64;i++) acc[i]=0.f;
    int py = tid>>4, px = tid&15;
    for (int ci=0; ci<cin; ci++){
        __syncthreads();
        const float* inp = in + ((size_t)b*cin + ci)*HWc;
        for (int i = tid; i < 324; i += 256) {
            int y=i/18, x=i%18; int hh=h0+y, ww=w0+x;
            tile[i] = (hh>=0&&hh<Hd&&ww>=0&&ww<Wd) ? inp[hh*Wd+ww] : 0.f;
        }
        for (int i = tid; i < 576; i += 256) {
            int oc = i/9, t = i - oc*9;
            wl[i] = wgt[((size_t)oc*cin + ci)*9 + t];
        }
        __syncthreads();
        float v[9];
        #pragma unroll
        for (int dy=0;dy<3;dy++)
            #pragma unroll
            for (int dx=0;dx<3;dx++)
                v[dy*3+dx] = tile[(py+dy)*18 + px+dx];
        #pragma unroll
        for (int oc=0;oc<64;oc++){
            float a = acc[oc];
            #pragma unroll
            for (int t=0;t<9;t++) a = fmaf(wl[oc*9+t], v[t], a);
            acc[oc]=a;
        }
    }
    int hh = h0+1+py, ww = w0+1+px;
    int p = hh*Wd + ww;
    #pragma unroll
    for (int g4=0; g4<16; g4++){
        half4 hv;
        #pragma unroll
        for (int reg=0; reg<4; reg++){
            int oc = g4*4+reg;
            float y = fmaf(acc[oc], sc[oc], sh[oc]);
            hv[reg] = (_Float16)fmaxf(y, 0.f);
        }
        *(half4*)&outp4[(((size_t)b*16+g4)*HWc + p)*4] = hv;
    }
}

// ---------------------------------------------------------------------------
// z maps from pack4 x1: z_t = sum_c down2_w[c,t]*x1[c] (and z1 for down1).
// ---------------------------------------------------------------------------
__global__ __launch_bounds__(256) void zmaps_kernel(const _Float16* __restrict__ x1p,
    const float* __restrict__ w2, const float* __restrict__ w1,
    float* __restrict__ z, float* __restrict__ z1)
{
    int idx = blockIdx.x*256 + threadIdx.x;
    int b = idx >> 14; int p = idx & 16383;
    const _Float16* xb = x1p + (size_t)b*16*HWc*4;
    float a2[9], a1[9];
    #pragma unroll
    for (int t=0;t<9;t++){ a2[t]=0.f; a1[t]=0.f; }
    for (int g4=0; g4<16; g4++){
        half4 v = *(const half4*)&xb[((size_t)g4*HWc + p)*4];
        #pragma unroll
        for (int k=0;k<4;k++){
            int c = g4*4+k;
            float val = (float)v[k];
            #pragma unroll
            for (int t=0;t<9;t++){
                a2[t] = fmaf(w2[c*9+t], val, a2[t]);
                a1[t] = fmaf(w1[c*9+t], val, a1[t]);
            }
        }
    }
    #pragma unroll
    for (int t=0;t<9;t++){
        z [((size_t)b*9+t)*HWc + p] = a2[t];
        z1[((size_t)b*9+t)*HWc + p] = a1[t];
    }
}

__global__ __launch_bounds__(256) void xin_kernel(const float* __restrict__ z1,
    const float* __restrict__ b1p, float* __restrict__ xin)
{
    int idx = blockIdx.x*256+threadIdx.x;
    int b=idx>>14; int p=idx&16383;
    int i=p>>7, j=p&127;
    float acc = b1p[0];
    #pragma unroll
    for (int t=0;t<9;t++){
        int ii=i+t/3-1, jj=j+t%3-1;
        if (ii>=0&&ii<Hd&&jj>=0&&jj<Wd)
            acc += z1[((size_t)b*9+t)*HWc + ii*Wd+jj];
    }
    xin[idx]=acc;
}

// ---------------------------------------------------------------------------
// Fused upsample+conv -> Haar DWT -> cA, E
// ---------------------------------------------------------------------------
__global__ __launch_bounds__(256) void dwt_kernel(const float* __restrict__ z,
    const float* __restrict__ b2p, float* __restrict__ cA, float* __restrict__ Eo)
{
    int idx = blockIdx.x*256 + threadIdx.x;
    int b = idx >> 14; int p = idx & 16383;
    int u = p >> 7, v = p & 127;
    float b2 = b2p[0];
    int rlo[4], rhi[4]; float rf[4]; bool rv[4];
    int clo[4], chi[4]; float cf[4]; bool cvv[4];
    #pragma unroll
    for (int k=0;k<4;k++){
        int r = 2*u - 1 + k;
        rv[k] = (r>=0 && r<256);
        int rr = rv[k] ? r : 0;
        float cc = ((float)rr * 127.0f) / 255.0f;
        int lo = (int)cc;
        rlo[k]=lo; rhi[k]=min(lo+1,127); rf[k]=cc-(float)lo;
        int s = 2*v - 1 + k;
        cvv[k] = (s>=0 && s<256);
        int ss = cvv[k] ? s : 0;
        float c2 = ((float)ss * 127.0f) / 255.0f;
        int lo2=(int)c2;
        clo[k]=lo2; chi[k]=min(lo2+1,127); cf[k]=c2-(float)lo2;
    }
    float Xin[4] = {b2,b2,b2,b2};
    #pragma unroll
    for (int t=0;t<9;t++){
        int dy=t/3, dx=t%3;
        const float* zp = z + ((size_t)b*9 + t)*HWc;
        #pragma unroll
        for (int e=0;e<4;e++){
            int ey=e>>1, ex=e&1;
            int k=ey+dy, l=ex+dx;
            if (rv[k] && cvv[l]){
                const float* row0 = zp + rlo[k]*Wd;
                const float* row1 = zp + rhi[k]*Wd;
                float v00=row0[clo[l]], v01=row0[chi[l]];
                float v10=row1[clo[l]], v11=row1[chi[l]];
                float fc_=cf[l], fr_=rf[k];
                float top = v00*(1.0f-fc_) + v01*fc_;
                float bot = v10*(1.0f-fc_) + v11*fc_;
                Xin[e] += top*(1.0f-fr_) + bot*fr_;
            }
        }
    }
    float a=Xin[0], bb=Xin[1], c_=Xin[2], d_=Xin[3];
    float LL=0.5f*( a+bb+c_+d_);
    float LH=0.5f*(-a-bb+c_+d_);
    float HL=0.5f*(-a+bb-c_+d_);
    float HH=0.5f*( a-bb-c_+d_);
    cA[(size_t)b*HWc + p] = LL;
    Eo[(size_t)b*HWc + p] = fabsf(LH)+fabsf(HL)+fabsf(HH);
}

__global__ __launch_bounds__(256) void wtgab_kernel(const float* __restrict__ cA,
    const float* __restrict__ xin, const float* __restrict__ wtw, const float* __restrict__ wtb,
    float* __restrict__ wtgab)
{
    __shared__ float gm[49];
    int tid=threadIdx.x;
    if (tid<49){
        int ky=tid/7, kx=tid%7;
        float yy=(float)(ky-3), xx=(float)(kx-3);
        float s=0.f;
        for (int t=0;t<4;t++){
            float theta = (float)t * 0.7853981633974483f;
            float ct=cosf(theta), st=sinf(theta);
            float xt = xx*ct + yy*st;
            float yt = -xx*st + yy*ct;
            s += expf(-0.5f*(xt*xt*(1.0f/16.0f) + yt*yt*(1.0f/64.0f))) * cosf(0.6283185307179586f*xt);
        }
        gm[tid]=0.25f*s;
    }
    __syncthreads();
    int idx = blockIdx.x*256+tid;
    int b=idx>>14; int p=idx&16383;
    int i=p>>7, j=p&127;
    float wacc = wtb[0];
    #pragma unroll
    for (int t=0;t<9;t++){
        int ii=i+t/3-1, jj=j+t%3-1;
        if (ii>=0&&ii<Hd&&jj>=0&&jj<Wd)
            wacc = fmaf(wtw[t], cA[b*HWc + ii*Wd+jj], wacc);
    }
    float g=0.f;
    for (int k=0;k<49;k++){
        int ii=i+k/7-3, jj=j+k%7-3;
        if (ii>=0&&ii<Hd&&jj>=0&&jj<Wd)
            g = fmaf(gm[k], xin[b*HWc + ii*Wd+jj], g);
    }
    wtgab[((size_t)b*2)*HWc + p] = wacc;
    wtgab[((size_t)b*2+1)*HWc + p] = 1.0f/(1.0f+expf(-g));
}

// ---------------------------------------------------------------------------
// CBAM: per-(b,g4) channel pooling from pack4 fusion.
// ---------------------------------------------------------------------------
__global__ __launch_bounds__(256) void pool_kernel(const _Float16* __restrict__ fp4,
    float* __restrict__ pavg, float* __restrict__ pmax)
{
    int b = blockIdx.x >> 4, g4 = blockIdx.x & 15;
    int tid = threadIdx.x;
    const _Float16* p = fp4 + ((size_t)b*16 + g4)*HWc*4;
    float s[4] = {0,0,0,0};
    float m[4] = {-3.4e38f,-3.4e38f,-3.4e38f,-3.4e38f};
    for (int i=tid;i<HWc;i+=256){
        half4 v = *(const half4*)&p[(size_t)i*4];
        #pragma unroll
        for (int k=0;k<4;k++){ float u=(float)v[k]; s[k]+=u; m[k]=fmaxf(m[k],u); }
    }
    __shared__ float ss[4][256], sm[4][256];
    #pragma unroll
    for (int k=0;k<4;k++){ ss[k][tid]=s[k]; sm[k][tid]=m[k]; }
    __syncthreads();
    for (int st=128; st>0; st>>=1){
        if (tid<st){
            #pragma unroll
            for (int k=0;k<4;k++){
                ss[k][tid]+=ss[k][tid+st];
                sm[k][tid]=fmaxf(sm[k][tid],sm[k][tid+st]);
            }
        }
        __syncthreads();
    }
    if (tid<4){
        pavg[b*64 + g4*4 + tid] = ss[tid][0]*(1.0f/16384.0f);
        pmax[b*64 + g4*4 + tid] = sm[tid][0];
    }
}

__global__ void mlp_kernel(const float* __restrict__ pavg, const float* __restrict__ pmax,
    const float* __restrict__ fc1, const float* __restrict__ fc2, float* __restrict__ ca)
{
    int b = blockIdx.x; int tid = threadIdx.x; // 64 threads
    __shared__ float hs[4];
    if (tid < 4){
        float sa_=0.f, sm_=0.f;
        for (int c=0;c<64;c++){
            float w = fc1[tid*64+c];
            sa_ = fmaf(w, pavg[b*64+c], sa_);
            sm_ = fmaf(w, pmax[b*64+c], sm_);
        }
        hs[tid] = fmaxf(sa_,0.f) + fmaxf(sm_,0.f);
    }
    __syncthreads();
    float o = 0.f;
    #pragma unroll
    for (int j=0;j<4;j++) o = fmaf(fc2[tid*4+j], hs[j], o);
    ca[b*64+tid] = 1.0f/(1.0f+expf(-o));
}

// spatial stats of fusion*ca (read-only; fusion not modified)
__global__ __launch_bounds__(256) void spstats_kernel(const _Float16* __restrict__ fp4,
    const float* __restrict__ ca, float* __restrict__ spmean, float* __restrict__ spmax)
{
    int idx = blockIdx.x*256+threadIdx.x;
    int b = idx>>14; int p = idx&16383;
    const _Float16* fb = fp4 + (size_t)b*16*HWc*4;
    const float* cp = ca + b*64;
    float s=0.f, m=-3.4e38f;
    for (int g4=0; g4<16; g4++){
        half4 v = *(const half4*)&fb[((size_t)g4*HWc + p)*4];
        #pragma unroll
        for (int k=0;k<4;k++){
            float u = (float)v[k] * cp[g4*4+k];
            s += u; m = fmaxf(m, u);
        }
    }
    spmean[idx] = s*(1.0f/64.0f);
    spmax[idx] = m;
}

__global__ __launch_bounds__(256) void spconv_kernel(const float* __restrict__ spmean,
    const float* __restrict__ spmax, const float* __restrict__ spw, float* __restrict__ sa)
{
    int idx = blockIdx.x*256+threadIdx.x;
    int b=idx>>14; int p=idx&16383;
    int i=p>>7, j=p&127;
    float acc=0.f;
    for (int k=0;k<49;k++){
        int ky=k/7-3, kx=k%7-3;
        int ii=i+ky, jj=j+kx;
        if (ii>=0&&ii<Hd&&jj>=0&&jj<Wd){
            int q = b*HWc + ii*Wd+jj;
            acc = fmaf(spw[k],    spmean[q], acc);
            acc = fmaf(spw[49+k], spmax[q], acc);
        }
    }
    sa[idx] = 1.0f/(1.0f+expf(-acc));
}

// ---------------------------------------------------------------------------
extern "C" void kernel_launch(void* const* d_in, const int* in_sizes, int n_in,
                              void* d_out, int out_size, void* d_ws, size_t ws_size,
                              hipStream_t stream)
{
    const float* x         = (const float*)d_in[0];
    const float* conv_in_w = (const float*)d_in[1];
    const float* bn1_g = (const float*)d_in[2];
    const float* bn1_b = (const float*)d_in[3];
    const float* bn1_m = (const float*)d_in[4];
    const float* bn1_v = (const float*)d_in[5];
    const float* down1_w = (const float*)d_in[6];
    const float* down1_b = (const float*)d_in[7];
    const float* down2_w = (const float*)d_in[8];
    const float* down2_b = (const float*)d_in[9];
    const float* wt_w = (const float*)d_in[10];
    const float* wt_b = (const float*)d_in[11];
    const float* edge_w = (const float*)d_in[12];
    const float* edge_b = (const float*)d_in[13];
    const float* up_w = (const float*)d_in[14];
    const float* bn2_g = (const float*)d_in[15];
    const float* bn2_b = (const float*)d_in[16];
    const float* bn2_m = (const float*)d_in[17];
    const float* bn2_v = (const float*)d_in[18];
    const float* combine_w = (const float*)d_in[19];
    const float* combine_b = (const float*)d_in[20];
    const float* fc1 = (const float*)d_in[21];
    const float* fc2 = (const float*)d_in[22];
    const float* spw = (const float*)d_in[23];
    const float* out_w = (const float*)d_in[24];
    const float* bn3_g = (const float*)d_in[25];
    const float* bn3_b = (const float*)d_in[26];
    const float* bn3_m = (const float*)d_in[27];
    const float* bn3_v = (const float*)d_in[28];
    float* out = (float*)d_out;
    float* ws = (float*)d_ws;

    // fp32 scratch
    float* z       = ws;                   // 2359296
    float* z1      = z + 2359296;
    float* xin     = z1 + 2359296;         // 262144
    float* cA      = xin + 262144;
    float* Ebuf    = cA + 262144;
    float* wtgab   = Ebuf + 262144;        // 524288
    float* spmean  = wtgab + 524288;
    float* spmaxb  = spmean + 262144;
    float* sabuf   = spmaxb + 262144;
    float* pavg    = sabuf + 262144;       // 1024
    float* pmaxb   = pavg + 1024;
    float* cab     = pmaxb + 1024;
    // f16 pack4 tensors (each 16*16*16384*4 = 16777216 f16)
    _Float16* xp      = (_Float16*)(cab + 1024);
    _Float16* x1p     = xp + 16777216;
    _Float16* f1p     = x1p + 16777216;
    _Float16* fp      = f1p + 16777216;
    // f16 weight fragments
    _Float16* wf_in   = fp + 16777216;     // 36864
    _Float16* wf_out  = wf_in + 36864;
    _Float16* wf_comb = wf_out + 36864;    // 73728

    prep_wfrag_kernel<<<144, 256, 0, stream>>>(conv_in_w, wf_in, 64);
    prep_wfrag_kernel<<<144, 256, 0, stream>>>(out_w, wf_out, 64);
    prep_wfrag_kernel<<<288, 256, 0, stream>>>(combine_w, wf_comb, 128);
    pack4_kernel<<<1024, 256, 0, stream>>>(x, xp);

    dim3 cgrid(64, 16);
    // x1 = relu(bn1(conv_in(x)))
    mfma_conv64_kernel<<<cgrid, 256, 0, stream>>>(xp, wf_in, bn1_g,bn1_b,bn1_m,bn1_v,
                                                  nullptr, nullptr, x1p, nullptr);
    zmaps_kernel<<<1024, 256, 0, stream>>>(x1p, down2_w, down1_w, z, z1);
    xin_kernel<<<1024, 256, 0, stream>>>(z1, down1_b, xin);
    dwt_kernel<<<1024, 256, 0, stream>>>(z, down2_b, cA, Ebuf);
    wtgab_kernel<<<1024, 256, 0, stream>>>(cA, xin, wt_w, wt_b, wtgab);
    conv3x3_bn_kernel<<<cgrid, 256, 0, stream>>>(wtgab, up_w, bn2_g,bn2_b,bn2_m,bn2_v, f1p, 2);
    mfma_combine_kernel<<<cgrid, 256, 0, stream>>>(f1p, Ebuf, x1p, edge_w, edge_b,
                                                   wf_comb, combine_b, fp);
    pool_kernel<<<256, 256, 0, stream>>>(fp, pavg, pmaxb);
    mlp_kernel<<<16, 64, 0, stream>>>(pavg, pmaxb, fc1, fc2, cab);
    spstats_kernel<<<1024, 256, 0, stream>>>(fp, cab, spmean, spmaxb);
    spconv_kernel<<<1024, 256, 0, stream>>>(spmean, spmaxb, spw, sabuf);
    // out = relu(bn3(conv(fusion*ca*sa, out_w)))
    mfma_conv64_kernel<<<cgrid, 256, 0, stream>>>(fp, wf_out, bn3_g,bn3_b,bn3_m,bn3_v,
                                                  sabuf, cab, nullptr, out);
}